// Round 5
// baseline (6639.119 us; speedup 1.0000x reference)
//
#include <hip/hip_runtime.h>
#include <stdint.h>

// DCRNN 2-layer DCGRU, MI355X. R5: S^2 precompute fuses the two diffusion
// S-mults per support into one MFMA phase (Z = S*YA + S^2*YB), killing the
// I-buffer RMW and 3 barriers/step. Stride-68 LDS diet + dedicated RH plane
// lets gates overlap the next group's P1. Producer/consumer layer pipeline
// across 64 blocks as R4. Split-bf16 hi/lo 3-term numerics throughout.

typedef short short8 __attribute__((ext_vector_type(8)));
typedef float float4v __attribute__((ext_vector_type(4)));
typedef unsigned short ushort4v __attribute__((ext_vector_type(4)));
typedef unsigned int uint4v __attribute__((ext_vector_type(4)));

#define MF(a,b,c) __builtin_amdgcn_mfma_f32_16x16x32_bf16(a,b,c,0,0,0)

__device__ __forceinline__ unsigned short f2bf(float v){
  unsigned int x = __builtin_bit_cast(unsigned int, v);
  x += 0x7FFFu + ((x >> 16) & 1u);
  return (unsigned short)(x >> 16);
}
__device__ __forceinline__ float bf2f(unsigned short h){
  unsigned int x = ((unsigned int)h) << 16;
  return __builtin_bit_cast(float, x);
}
__device__ __forceinline__ void cvt_hilo(const float4v v, ushort4v& oh, ushort4v& ol){
#pragma unroll
  for (int r=0;r<4;r++){ unsigned short h=f2bf(v[r]); oh[r]=h; ol[r]=f2bf(v[r]-bf2f(h)); }
}

// ---- LDS (u16 units). pair planes: hi at base, lo at +PLO; row stride 68 ----
#define PLO 4352
#define XP  0
#define HP  8704
#define RH  17408
#define YS0 26112   // YA sup0 (j1)
#define YS1 34816   // YB sup0 (j2, pre-scaled 2x)
#define YS2 43520   // YA sup1 (j3)
#define YS3 52224   // YB sup1 (j4, pre-scaled 2x)
#define Z0F 30464   // f32 index (u16 60928), stride 68
#define Z1F 34816   // f32 index
#define LDS_BYTES 156672

// ---- ws offsets (u16) ----
#define WSF_S2   16384
#define WSF_WG0  32768
#define WSF_WC0  196608
#define WSF_WG1  278528
#define WSF_WC1  442368
#define WSF_CAP  524288
#define WSF_FLAG 655360   // int flags[32][128]
#define WSF_DONE 663552   // int done[32]
#define WSF_SLOT 663616   // 32*16 slots * 4096 u32 (hi | lo<<16)
#define WSF_SQS  4857920  // 2*4096 f32 scratch (S0^2, S1^2)

#define TB(grp,j,nt) ((((grp)*5+(j))*4+(nt))*4)

__device__ __forceinline__ void store_Y(unsigned short* lds_, int buf, int nt,
                                        int fc, int qd, const float4v* acc){
#pragma unroll
  for (int Mt=0;Mt<4;Mt++){
    ushort4v oh,ol; cvt_hilo(acc[Mt],oh,ol);
    const int o = buf + (16*nt+fc)*68 + 16*Mt + 4*qd;
    *(ushort4v*)(lds_+o)=oh; *(ushort4v*)(lds_+o+PLO)=ol;
  }
}

// P1: one A pass -> gacc(j0,+bias, lo waves) + YA/YB tiles
__device__ __forceinline__ void p1_group(unsigned short* lds_,
    const unsigned short* __restrict__ wfr, int grp, int p0, int p1,
    float bias, float4v* gacc, int w, int ln, int fc, int qd)
{
  const int nt = w & 3;
  const bool lo = (w < 4);
  float4v aY0[4], aY1[4];
#pragma unroll
  for (int Mt=0;Mt<4;Mt++){
    aY0[Mt]=(float4v){0.f,0.f,0.f,0.f};
    aY1[Mt]=(float4v){0.f,0.f,0.f,0.f};
  }
  if (lo){
#pragma unroll
    for (int Mt=0;Mt<4;Mt++) gacc[Mt]=(float4v){bias,bias,bias,bias};
  }
  const int tbG = TB(grp,0,nt);
  const int tbA = lo ? TB(grp,1,nt) : TB(grp,2,nt);
  const int tbB = lo ? TB(grp,3,nt) : TB(grp,4,nt);
#pragma unroll
  for (int kt=0;kt<4;kt++){
    const int pb = (kt<2)? p0 : p1;
    short8 ah[4], al[4];
#pragma unroll
    for (int Mt=0;Mt<4;Mt++){
      const int o = pb + (16*Mt+fc)*68 + 32*(kt&1) + 8*qd;
      ah[Mt]=*(const short8*)(lds_+o);
      al[Mt]=*(const short8*)(lds_+o+PLO);
    }
    if (lo){
      const unsigned short* wb = wfr + (size_t)((tbG+kt)*2)*512 + ln*8;
      short8 bh=*(const short8*)wb, bl=*(const short8*)(wb+512);
#pragma unroll
      for (int Mt=0;Mt<4;Mt++){
        gacc[Mt]=MF(ah[Mt],bh,gacc[Mt]); gacc[Mt]=MF(ah[Mt],bl,gacc[Mt]);
        gacc[Mt]=MF(al[Mt],bh,gacc[Mt]);
      }
    }
    {
      const unsigned short* wb = wfr + (size_t)((tbA+kt)*2)*512 + ln*8;
      short8 bh=*(const short8*)wb, bl=*(const short8*)(wb+512);
#pragma unroll
      for (int Mt=0;Mt<4;Mt++){
        aY0[Mt]=MF(ah[Mt],bh,aY0[Mt]); aY0[Mt]=MF(ah[Mt],bl,aY0[Mt]);
        aY0[Mt]=MF(al[Mt],bh,aY0[Mt]);
      }
    }
    {
      const unsigned short* wb = wfr + (size_t)((tbB+kt)*2)*512 + ln*8;
      short8 bh=*(const short8*)wb, bl=*(const short8*)(wb+512);
#pragma unroll
      for (int Mt=0;Mt<4;Mt++){
        aY1[Mt]=MF(ah[Mt],bh,aY1[Mt]); aY1[Mt]=MF(ah[Mt],bl,aY1[Mt]);
        aY1[Mt]=MF(al[Mt],bh,aY1[Mt]);
      }
    }
  }
  store_Y(lds_, lo? YS0 : YS1, nt, fc, qd, aY0);
  store_Y(lds_, lo? YS2 : YS3, nt, fc, qd, aY1);
}

// P2 fused: Z_sup = S_sup @ YA_sup + S_sup^2 @ YB_sup  -> fp32 Z plane
__device__ __forceinline__ void p2_fused(unsigned short* lds_,
    const short8* sfA, const short8* sfB, int sup, int mt, int fc, int qd)
{
  const int ya = sup? YS2 : YS0;
  const int yb = sup? YS3 : YS1;
  float* zf = (float*)lds_ + (sup? Z1F : Z0F);
#pragma unroll
  for (int nt=0;nt<4;nt++){
    float4v acc = {0.f,0.f,0.f,0.f};
#pragma unroll
    for (int kt=0;kt<2;kt++){
      {
        const int bo = ya + (16*nt+fc)*68 + 32*kt + 8*qd;
        short8 bh=*(const short8*)(lds_+bo), bl=*(const short8*)(lds_+bo+PLO);
        acc=MF(sfA[kt*2+0],bh,acc); acc=MF(sfA[kt*2+0],bl,acc); acc=MF(sfA[kt*2+1],bh,acc);
      }
      {
        const int bo = yb + (16*nt+fc)*68 + 32*kt + 8*qd;
        short8 bh=*(const short8*)(lds_+bo), bl=*(const short8*)(lds_+bo+PLO);
        acc=MF(sfB[kt*2+0],bh,acc); acc=MF(sfB[kt*2+0],bl,acc); acc=MF(sfB[kt*2+1],bh,acc);
      }
    }
    *(float4v*)(zf + (16*nt+fc)*68 + 16*mt + 4*qd) = acc;
  }
}

__device__ __forceinline__ void read_pre(const unsigned short* lds_,
    const float4v* gacc, float4v* pre, int w, int fc, int qd)
{
  const float* lf = (const float*)lds_;
#pragma unroll
  for (int Mt=0;Mt<4;Mt++){
    float4v za = *(const float4v*)(lf + Z0F + (16*w+fc)*68 + 16*Mt + 4*qd);
    float4v zb = *(const float4v*)(lf + Z1F + (16*w+fc)*68 + 16*Mt + 4*qd);
    pre[Mt] = gacc[Mt] + za + zb;
  }
}

__device__ __forceinline__ void scatter_plane(unsigned short* lds_, int plane,
    int w, int fc, int qd, const ushort4v* oh, const ushort4v* ol)
{
#pragma unroll
  for (int Mt=0;Mt<4;Mt++){
#pragma unroll
    for (int r=0;r<4;r++){
      const int o = plane + (16*Mt+4*qd+r)*68 + 16*w+fc;
      lds_[o] = oh[Mt][r]; lds_[o+PLO] = ol[Mt][r];
    }
  }
}

__global__ void __launch_bounds__(512, 2)
dcrnn_main(const float* __restrict__ input_seq, const int* __restrict__ seq_lengths,
           const float* __restrict__ bg0, const float* __restrict__ bc0,
           const float* __restrict__ bg1, const float* __restrict__ bc1,
           const float* __restrict__ Wp, const float* __restrict__ bp,
           unsigned short* __restrict__ ws, float* __restrict__ out)
{
  extern __shared__ unsigned short lds_[];
  const int tid = threadIdx.x;
  const int w = tid>>6, ln = tid&63, fc = ln&15, qd = ln>>4;
  const int role = blockIdx.x >> 5;   // 0 = layer0 producer, 1 = layer1 consumer
  const int b = blockIdx.x & 31;

  const unsigned short* frags = ws;
  int* flags = (int*)(ws + WSF_FLAG) + b*128;
  int* done  = (int*)(ws + WSF_DONE) + b;
  unsigned short* capb = ws + WSF_CAP + (size_t)b*4096;
  unsigned int* slots = (unsigned int*)(ws + WSF_SLOT);

  // zero HP pair: u16 [8704,17408) -> u32 [4352,8704)
  { unsigned int* l32 = (unsigned int*)lds_;
    for (int i=4352+tid; i<8704; i+=512) l32[i]=0u; }

  // S and S^2 frags for this wave's (sup, mt)
  const int sup = (w>>2)&1, mt = w&3;
  short8 sfA[4], sfB[4];
#pragma unroll
  for (int kt=0;kt<2;kt++)
#pragma unroll
    for (int pl=0;pl<2;pl++){
      const size_t o = (size_t)((((sup*2+pl)*4+mt)*2+kt)*512 + ln*8);
      sfA[kt*2+pl] = *(const short8*)(frags + o);
      sfB[kt*2+pl] = *(const short8*)(frags + WSF_S2 + o);
    }

  const unsigned short* WGf = frags + (role? WSF_WG1 : WSF_WG0);
  const unsigned short* WCf = frags + (role? WSF_WC1 : WSF_WC0);
  const float* bg = role? bg1 : bg0;
  const float* bc = role? bc1 : bc0;
  const int gcol = 16*w+fc;
  const float brv = (w<4)? bg[gcol]    : 0.f;
  const float buv = (w<4)? bg[64+gcol] : 0.f;
  const float bcv = (w<4)? bc[gcol]    : 0.f;

  int tl = 0;
  if (role){ tl = seq_lengths[b]-1; tl = tl<0?0:(tl>127?127:tl); }

  float4v h_old[4], uv[4], gaccR[4], gaccU[4], gaccC[4];
#pragma unroll
  for (int Mt=0;Mt<4;Mt++) h_old[Mt]=(float4v){0.f,0.f,0.f,0.f};
  __syncthreads();

#pragma unroll 1
  for (int t=0; t<128; ++t){
    // ---- phase 1: acquire input into XP ----
    if (role==0){
      if (t>=16 && tid==0){
        while ((int)__hip_atomic_load(done, __ATOMIC_ACQUIRE, __HIP_MEMORY_SCOPE_AGENT) < t-15)
          __builtin_amdgcn_s_sleep(1);
      }
      const int node = tid>>3, f0 = (tid&7)*8;
      const float* src = input_seq + (((size_t)b*128 + t)*64 + node)*64 + f0;
      float4v v0 = *(const float4v*)(src);
      float4v v1 = *(const float4v*)(src+4);
      short8 hh, ll;
#pragma unroll
      for (int j=0;j<4;j++){
        unsigned short h0=f2bf(v0[j]); hh[j]=(short)h0; ll[j]=(short)f2bf(v0[j]-bf2f(h0));
        unsigned short h1=f2bf(v1[j]); hh[4+j]=(short)h1; ll[4+j]=(short)f2bf(v1[j]-bf2f(h1));
      }
      *(short8*)(lds_ + XP + node*68 + f0) = hh;
      *(short8*)(lds_ + XP + PLO + node*68 + f0) = ll;
      __syncthreads();
    } else {
      if (tid==0){
        while (__hip_atomic_load(&flags[t], __ATOMIC_ACQUIRE, __HIP_MEMORY_SCOPE_AGENT) != t+1)
          __builtin_amdgcn_s_sleep(1);
        __threadfence();
      }
      __syncthreads();
      if (w<4){
        const unsigned int* sl = slots + ((size_t)(b*16 + (t&15)))*4096 + (w*64+ln)*16;
#pragma unroll
        for (int Mt=0;Mt<4;Mt++){
          uint4v v = *(const uint4v*)(sl + Mt*4);
#pragma unroll
          for (int r=0;r<4;r++){
            const int o = XP + (16*Mt+4*qd+r)*68 + gcol;
            lds_[o] = (unsigned short)(v[r] & 0xffffu);
            lds_[o+PLO] = (unsigned short)(v[r] >> 16);
          }
        }
      }
      __syncthreads();
      if (tid==0)
        __hip_atomic_store(done, t+1, __ATOMIC_RELEASE, __HIP_MEMORY_SCOPE_AGENT);
    }

    // ---- phase 2: P1 r ----
    p1_group(lds_, WGf, 0, XP, HP, brv, gaccR, w, ln, fc, qd);
    __syncthreads();
    // ---- phase 3: P2 r (Z_r) ----
    p2_fused(lds_, sfA, sfB, sup, mt, fc, qd);
    __syncthreads();

    // ---- phase 4: P1 u + gate r (rh -> RH plane) ----
    p1_group(lds_, WGf, 1, XP, HP, buv, gaccU, w, ln, fc, qd);
    if (w<4){
      float4v pre[4]; read_pre(lds_, gaccR, pre, w, fc, qd);
      ushort4v oh[4], ol[4];
#pragma unroll
      for (int Mt=0;Mt<4;Mt++){
        float4v rh;
#pragma unroll
        for (int r=0;r<4;r++){
          float rv = 1.f/(1.f+__expf(-pre[Mt][r]));
          rh[r] = rv*h_old[Mt][r];
        }
        cvt_hilo(rh, oh[Mt], ol[Mt]);
      }
      scatter_plane(lds_, RH, w, fc, qd, oh, ol);
    }
    __syncthreads();
    // ---- phase 5: P2 u (Z_u overwrites Z_r, consumed) ----
    p2_fused(lds_, sfA, sfB, sup, mt, fc, qd);
    __syncthreads();

    // ---- phase 6: P1 c (A = XP | RH) + gate u ----
    p1_group(lds_, WCf, 0, XP, RH, bcv, gaccC, w, ln, fc, qd);
    if (w<4){
      float4v pre[4]; read_pre(lds_, gaccU, pre, w, fc, qd);
#pragma unroll
      for (int Mt=0;Mt<4;Mt++)
#pragma unroll
        for (int r=0;r<4;r++) uv[Mt][r] = 1.f/(1.f+__expf(-pre[Mt][r]));
    }
    __syncthreads();
    // ---- phase 7: P2 c ----
    p2_fused(lds_, sfA, sfB, sup, mt, fc, qd);
    __syncthreads();

    // ---- phase 8: update ----
    if (w<4){
      float4v pre[4]; read_pre(lds_, gaccC, pre, w, fc, qd);
      ushort4v oh[4], ol[4];
#pragma unroll
      for (int Mt=0;Mt<4;Mt++){
        float4v hn;
#pragma unroll
        for (int r=0;r<4;r++){
          float x = fminf(pre[Mt][r], 15.f);
          float e = __expf(2.f*x);
          float cv = (e-1.f)/(e+1.f);
          float u1 = uv[Mt][r];
          hn[r] = u1*h_old[Mt][r] + (1.f-u1)*cv;
        }
        h_old[Mt] = hn;
        cvt_hilo(hn, oh[Mt], ol[Mt]);
      }
      scatter_plane(lds_, HP, w, fc, qd, oh, ol);
      if (role==0){
        unsigned int* sl = slots + ((size_t)(b*16 + (t&15)))*4096 + (w*64+ln)*16;
#pragma unroll
        for (int Mt=0;Mt<4;Mt++){
          uint4v pk;
#pragma unroll
          for (int r=0;r<4;r++)
            pk[r] = (unsigned int)oh[Mt][r] | ((unsigned int)ol[Mt][r] << 16);
          *(uint4v*)(sl + Mt*4) = pk;
        }
      } else if (t==tl){
#pragma unroll
        for (int Mt=0;Mt<4;Mt++)
#pragma unroll
          for (int r=0;r<4;r++)
            capb[(16*Mt+4*qd+r)*64 + gcol] = oh[Mt][r];
      }
    }
    __syncthreads();
    if (role==0 && tid==0){
      __threadfence();
      __hip_atomic_store(&flags[t], t+1, __ATOMIC_RELEASE, __HIP_MEMORY_SCOPE_AGENT);
    }
  }

  if (role==0) return;

  __threadfence();
  __syncthreads();
  // epilogue (consumer): logits = relu(last_h2) @ Wp + bp; max over nodes
  float* sc = (float*)lds_;
  if (tid < 64){
    const unsigned short* hpx = capb + tid*64;
    float4v acc = {bp[0], bp[1], bp[2], bp[3]};
#pragma unroll 1
    for (int ch = 0; ch < 64; ++ch){
      float h = fmaxf(bf2f(hpx[ch]), 0.f);
      const float4v wr = *(const float4v*)(Wp + ch*4);
      acc += h * wr;
    }
    sc[tid*4+0]=acc[0]; sc[tid*4+1]=acc[1]; sc[tid*4+2]=acc[2]; sc[tid*4+3]=acc[3];
  }
  __syncthreads();
  if (tid < 4){
    float m = sc[tid];
#pragma unroll 1
    for (int n=1;n<64;n++) m = fmaxf(m, sc[n*4 + tid]);
    out[b*4 + tid] = m;
  }
}

// ---- S^2 (fp32) into ws scratch ----
__global__ void __launch_bounds__(256)
dcrnn_sq(const float* __restrict__ S0, const float* __restrict__ S1,
         float* __restrict__ sqs)
{
  const float* S = blockIdx.x ? S1 : S0;
  float* D = sqs + blockIdx.x*4096;
  const int i = threadIdx.x >> 2, j0 = (threadIdx.x & 3)*16;
  float acc[16];
#pragma unroll
  for (int j=0;j<16;j++) acc[j]=0.f;
#pragma unroll 4
  for (int k=0;k<64;k++){
    float s = S[i*64+k];
    const float* row = S + k*64 + j0;
#pragma unroll
    for (int j=0;j<16;j++) acc[j] += s*row[j];
  }
#pragma unroll
  for (int j=0;j<16;j++) D[i*64+j0+j]=acc[j];
}

// ---- prep: S, S^2 frags (A-layout) + folded W frags (B-layout), hi/lo ----
__global__ void __launch_bounds__(256)
dcrnn_prep(const float* __restrict__ S0, const float* __restrict__ S1,
           const float* __restrict__ Wg0, const float* __restrict__ Wc0,
           const float* __restrict__ Wg1, const float* __restrict__ Wc1,
           const float* __restrict__ sqs, unsigned short* __restrict__ frags)
{
  const int uid = blockIdx.x*256 + threadIdx.x;
  if (uid >= 65536) return;
  short8 o;
  unsigned short* dst;
  if (uid < 4096){
    int r = uid & 2047;
    const bool issq = uid >= 2048;
    const int lane = r & 63; r >>= 6;
    const int kt = r & 1; r >>= 1;
    const int Mt = r & 3; r >>= 2;
    const int pl = r & 1; r >>= 1;
    const float* S = issq ? (sqs + r*4096) : (r ? S1 : S0);
    const int m  = 16*Mt + (lane & 15);
    const int k0 = 32*kt + 8*(lane >> 4);
#pragma unroll
    for (int j=0;j<8;j++){
      float v = S[m*64 + k0 + j];
      unsigned short hi = f2bf(v);
      o[j] = (short)(pl ? f2bf(v - bf2f(hi)) : hi);
    }
    dst = frags + (issq ? WSF_S2 : 0) + (size_t)(uid & 2047)*8;
  } else {
    int u2 = uid - 4096;
    const float* W; int wld; size_t base;
    if      (u2 < 20480){ W = Wg0; wld = 128; base = WSF_WG0; }
    else if (u2 < 30720){ W = Wc0; wld = 64;  base = WSF_WC0; u2 -= 20480; }
    else if (u2 < 51200){ W = Wg1; wld = 128; base = WSF_WG1; u2 -= 30720; }
    else                { W = Wc1; wld = 64;  base = WSF_WC1; u2 -= 51200; }
    const int lane = u2 & 63;
    const int pl   = (u2 >> 6) & 1;
    const int rest = u2 >> 7;                 // ((grp*5+j)*4+nt)*4+kt
    const int kt = rest & 3;
    const int nt = (rest >> 2) & 3;
    const int j  = (rest >> 4) % 5;
    const int grp= (rest >> 4) / 5;
    const int col = grp*64 + 16*nt + (lane & 15);
    const int k0  = 32*kt + 8*(lane >> 4);
#pragma unroll
    for (int jj=0;jj<8;jj++){
      const int k = k0 + jj;
      float v;
      if (j == 0)
        v = W[(size_t)k*wld + col] - W[(size_t)(256+k)*wld + col] - W[(size_t)(512+k)*wld + col];
      else {
        v = W[(size_t)(j*128 + k)*wld + col];
        if (j == 2 || j == 4) v *= 2.f;
      }
      unsigned short hi = f2bf(v);
      o[jj] = (short)(pl ? f2bf(v - bf2f(hi)) : hi);
    }
    dst = frags + base + (size_t)u2*8;
  }
  *(short8*)dst = o;
}

extern "C" void kernel_launch(void* const* d_in, const int* in_sizes, int n_in,
                              void* d_out, int out_size, void* d_ws, size_t ws_size,
                              hipStream_t stream) {
  const float* input_seq   = (const float*)d_in[0];
  const int*   seq_lengths = (const int*)  d_in[1];
  const float* S0  = (const float*)d_in[2];
  const float* S1  = (const float*)d_in[3];
  const float* Wg0 = (const float*)d_in[4];
  const float* bg0 = (const float*)d_in[5];
  const float* Wc0 = (const float*)d_in[6];
  const float* bc0 = (const float*)d_in[7];
  const float* Wg1 = (const float*)d_in[8];
  const float* bg1 = (const float*)d_in[9];
  const float* Wc1 = (const float*)d_in[10];
  const float* bc1 = (const float*)d_in[11];
  const float* Wp  = (const float*)d_in[12];
  const float* bp  = (const float*)d_in[13];

  unsigned short* ws = (unsigned short*)d_ws;
  float* sqs = (float*)(ws + WSF_SQS);

  dcrnn_sq<<<dim3(2), dim3(256), 0, stream>>>(S0, S1, sqs);
  dcrnn_prep<<<dim3(256), dim3(256), 0, stream>>>(S0, S1, Wg0, Wc0, Wg1, Wc1, sqs, ws);

  (void)hipFuncSetAttribute((const void*)dcrnn_main,
                            hipFuncAttributeMaxDynamicSharedMemorySize, LDS_BYTES);
  dcrnn_main<<<dim3(64), dim3(512), LDS_BYTES, stream>>>(
      input_seq, seq_lengths, bg0, bc0, bg1, bc1, Wp, bp, ws, (float*)d_out);
}

// Round 6
// 3215.388 us; speedup vs baseline: 2.0648x; 2.0648x over previous
//
#include <hip/hip_runtime.h>
#include <stdint.h>

// DCRNN 2-layer DCGRU, MI355X. R6 = R5 (S^2 fusion, 8 barriers/step,
// producer/consumer layer pipeline) with the R5 alignment regression fixed:
// LDS row stride back to 72 u16 = 144 B so every b128 row access stays
// 16B-aligned (stride-68 = 136 B made odd rows 8B-aligned -> split LDS ops,
// 2x issue). Dedicated RH + fp32 Z planes; exactly 160 KB LDS.

typedef short short8 __attribute__((ext_vector_type(8)));
typedef float float4v __attribute__((ext_vector_type(4)));
typedef unsigned short ushort4v __attribute__((ext_vector_type(4)));
typedef unsigned int uint4v __attribute__((ext_vector_type(4)));

#define MF(a,b,c) __builtin_amdgcn_mfma_f32_16x16x32_bf16(a,b,c,0,0,0)

__device__ __forceinline__ unsigned short f2bf(float v){
  unsigned int x = __builtin_bit_cast(unsigned int, v);
  x += 0x7FFFu + ((x >> 16) & 1u);
  return (unsigned short)(x >> 16);
}
__device__ __forceinline__ float bf2f(unsigned short h){
  unsigned int x = ((unsigned int)h) << 16;
  return __builtin_bit_cast(float, x);
}
__device__ __forceinline__ void cvt_hilo(const float4v v, ushort4v& oh, ushort4v& ol){
#pragma unroll
  for (int r=0;r<4;r++){ unsigned short h=f2bf(v[r]); oh[r]=h; ol[r]=f2bf(v[r]-bf2f(h)); }
}

// ---- LDS (u16). pair planes: hi at base, lo at +PLO; row stride 72 u16 ----
#define PLO 4608
#define XP  0
#define HP  9216
#define RH  18432
#define YS0 27648   // YA sup0 (j1)
#define YS1 36864   // YB sup0 (j2, pre-scaled 2x)
#define YS2 46080   // YA sup1 (j3)
#define YS3 55296   // YB sup1 (j4, pre-scaled 2x)
#define Z0F 32256   // f32 index (u16 64512), stride 68 floats
#define Z1F 36608
#define LDS_BYTES 163840

// ---- ws offsets (u16) ----
#define WSF_S2   16384
#define WSF_WG0  32768
#define WSF_WC0  196608
#define WSF_WG1  278528
#define WSF_WC1  442368
#define WSF_CAP  524288
#define WSF_FLAG 655360   // int flags[32][128]
#define WSF_DONE 663552   // int done[32]
#define WSF_SLOT 663616   // 32*16 slots * 4096 u32 (hi | lo<<16)
#define WSF_SQS  4857920  // 2*4096 f32 scratch (S0^2, S1^2)

#define TB(grp,j,nt) ((((grp)*5+(j))*4+(nt))*4)

__device__ __forceinline__ void store_Y(unsigned short* lds_, int buf, int nt,
                                        int fc, int qd, const float4v* acc){
#pragma unroll
  for (int Mt=0;Mt<4;Mt++){
    ushort4v oh,ol; cvt_hilo(acc[Mt],oh,ol);
    const int o = buf + (16*nt+fc)*72 + 16*Mt + 4*qd;
    *(ushort4v*)(lds_+o)=oh; *(ushort4v*)(lds_+o+PLO)=ol;
  }
}

// P1: one A pass -> gacc(j0,+bias, lo waves) + YA/YB tiles
__device__ __forceinline__ void p1_group(unsigned short* lds_,
    const unsigned short* __restrict__ wfr, int grp, int p0, int p1,
    float bias, float4v* gacc, int w, int ln, int fc, int qd)
{
  const int nt = w & 3;
  const bool lo = (w < 4);
  float4v aY0[4], aY1[4];
#pragma unroll
  for (int Mt=0;Mt<4;Mt++){
    aY0[Mt]=(float4v){0.f,0.f,0.f,0.f};
    aY1[Mt]=(float4v){0.f,0.f,0.f,0.f};
  }
  if (lo){
#pragma unroll
    for (int Mt=0;Mt<4;Mt++) gacc[Mt]=(float4v){bias,bias,bias,bias};
  }
  const int tbG = TB(grp,0,nt);
  const int tbA = lo ? TB(grp,1,nt) : TB(grp,2,nt);
  const int tbB = lo ? TB(grp,3,nt) : TB(grp,4,nt);
#pragma unroll
  for (int kt=0;kt<4;kt++){
    const int pb = (kt<2)? p0 : p1;
    short8 ah[4], al[4];
#pragma unroll
    for (int Mt=0;Mt<4;Mt++){
      const int o = pb + (16*Mt+fc)*72 + 32*(kt&1) + 8*qd;
      ah[Mt]=*(const short8*)(lds_+o);
      al[Mt]=*(const short8*)(lds_+o+PLO);
    }
    if (lo){
      const unsigned short* wb = wfr + (size_t)((tbG+kt)*2)*512 + ln*8;
      short8 bh=*(const short8*)wb, bl=*(const short8*)(wb+512);
#pragma unroll
      for (int Mt=0;Mt<4;Mt++){
        gacc[Mt]=MF(ah[Mt],bh,gacc[Mt]); gacc[Mt]=MF(ah[Mt],bl,gacc[Mt]);
        gacc[Mt]=MF(al[Mt],bh,gacc[Mt]);
      }
    }
    {
      const unsigned short* wb = wfr + (size_t)((tbA+kt)*2)*512 + ln*8;
      short8 bh=*(const short8*)wb, bl=*(const short8*)(wb+512);
#pragma unroll
      for (int Mt=0;Mt<4;Mt++){
        aY0[Mt]=MF(ah[Mt],bh,aY0[Mt]); aY0[Mt]=MF(ah[Mt],bl,aY0[Mt]);
        aY0[Mt]=MF(al[Mt],bh,aY0[Mt]);
      }
    }
    {
      const unsigned short* wb = wfr + (size_t)((tbB+kt)*2)*512 + ln*8;
      short8 bh=*(const short8*)wb, bl=*(const short8*)(wb+512);
#pragma unroll
      for (int Mt=0;Mt<4;Mt++){
        aY1[Mt]=MF(ah[Mt],bh,aY1[Mt]); aY1[Mt]=MF(ah[Mt],bl,aY1[Mt]);
        aY1[Mt]=MF(al[Mt],bh,aY1[Mt]);
      }
    }
  }
  store_Y(lds_, lo? YS0 : YS1, nt, fc, qd, aY0);
  store_Y(lds_, lo? YS2 : YS3, nt, fc, qd, aY1);
}

// P2 fused: Z_sup = S_sup @ YA_sup + S_sup^2 @ YB_sup  -> fp32 Z plane
__device__ __forceinline__ void p2_fused(unsigned short* lds_,
    const short8* sfA, const short8* sfB, int sup, int mt, int fc, int qd)
{
  const int ya = sup? YS2 : YS0;
  const int yb = sup? YS3 : YS1;
  float* zf = (float*)lds_ + (sup? Z1F : Z0F);
#pragma unroll
  for (int nt=0;nt<4;nt++){
    float4v acc = {0.f,0.f,0.f,0.f};
#pragma unroll
    for (int kt=0;kt<2;kt++){
      {
        const int bo = ya + (16*nt+fc)*72 + 32*kt + 8*qd;
        short8 bh=*(const short8*)(lds_+bo), bl=*(const short8*)(lds_+bo+PLO);
        acc=MF(sfA[kt*2+0],bh,acc); acc=MF(sfA[kt*2+0],bl,acc); acc=MF(sfA[kt*2+1],bh,acc);
      }
      {
        const int bo = yb + (16*nt+fc)*72 + 32*kt + 8*qd;
        short8 bh=*(const short8*)(lds_+bo), bl=*(const short8*)(lds_+bo+PLO);
        acc=MF(sfB[kt*2+0],bh,acc); acc=MF(sfB[kt*2+0],bl,acc); acc=MF(sfB[kt*2+1],bh,acc);
      }
    }
    *(float4v*)(zf + (16*nt+fc)*68 + 16*mt + 4*qd) = acc;
  }
}

__device__ __forceinline__ void read_pre(const unsigned short* lds_,
    const float4v* gacc, float4v* pre, int w, int fc, int qd)
{
  const float* lf = (const float*)lds_;
#pragma unroll
  for (int Mt=0;Mt<4;Mt++){
    float4v za = *(const float4v*)(lf + Z0F + (16*w+fc)*68 + 16*Mt + 4*qd);
    float4v zb = *(const float4v*)(lf + Z1F + (16*w+fc)*68 + 16*Mt + 4*qd);
    pre[Mt] = gacc[Mt] + za + zb;
  }
}

__device__ __forceinline__ void scatter_plane(unsigned short* lds_, int plane,
    int w, int fc, int qd, const ushort4v* oh, const ushort4v* ol)
{
#pragma unroll
  for (int Mt=0;Mt<4;Mt++){
#pragma unroll
    for (int r=0;r<4;r++){
      const int o = plane + (16*Mt+4*qd+r)*72 + 16*w+fc;
      lds_[o] = oh[Mt][r]; lds_[o+PLO] = ol[Mt][r];
    }
  }
}

__global__ void __launch_bounds__(512, 2)
dcrnn_main(const float* __restrict__ input_seq, const int* __restrict__ seq_lengths,
           const float* __restrict__ bg0, const float* __restrict__ bc0,
           const float* __restrict__ bg1, const float* __restrict__ bc1,
           const float* __restrict__ Wp, const float* __restrict__ bp,
           unsigned short* __restrict__ ws, float* __restrict__ out)
{
  extern __shared__ unsigned short lds_[];
  const int tid = threadIdx.x;
  const int w = tid>>6, ln = tid&63, fc = ln&15, qd = ln>>4;
  const int role = blockIdx.x >> 5;   // 0 = layer0 producer, 1 = layer1 consumer
  const int b = blockIdx.x & 31;

  const unsigned short* frags = ws;
  int* flags = (int*)(ws + WSF_FLAG) + b*128;
  int* done  = (int*)(ws + WSF_DONE) + b;
  unsigned short* capb = ws + WSF_CAP + (size_t)b*4096;
  unsigned int* slots = (unsigned int*)(ws + WSF_SLOT);

  // zero HP pair: u16 [9216,18432) -> u32 [4608,9216)
  { unsigned int* l32 = (unsigned int*)lds_;
    for (int i=4608+tid; i<9216; i+=512) l32[i]=0u; }

  // S and S^2 frags for this wave's (sup, mt)
  const int sup = (w>>2)&1, mt = w&3;
  short8 sfA[4], sfB[4];
#pragma unroll
  for (int kt=0;kt<2;kt++)
#pragma unroll
    for (int pl=0;pl<2;pl++){
      const size_t o = (size_t)((((sup*2+pl)*4+mt)*2+kt)*512 + ln*8);
      sfA[kt*2+pl] = *(const short8*)(frags + o);
      sfB[kt*2+pl] = *(const short8*)(frags + WSF_S2 + o);
    }

  const unsigned short* WGf = frags + (role? WSF_WG1 : WSF_WG0);
  const unsigned short* WCf = frags + (role? WSF_WC1 : WSF_WC0);
  const float* bg = role? bg1 : bg0;
  const float* bc = role? bc1 : bc0;
  const int gcol = 16*w+fc;
  const float brv = (w<4)? bg[gcol]    : 0.f;
  const float buv = (w<4)? bg[64+gcol] : 0.f;
  const float bcv = (w<4)? bc[gcol]    : 0.f;

  int tl = 0;
  if (role){ tl = seq_lengths[b]-1; tl = tl<0?0:(tl>127?127:tl); }

  float4v h_old[4], uv[4], gaccR[4], gaccU[4], gaccC[4];
#pragma unroll
  for (int Mt=0;Mt<4;Mt++) h_old[Mt]=(float4v){0.f,0.f,0.f,0.f};
  __syncthreads();

#pragma unroll 1
  for (int t=0; t<128; ++t){
    // ---- phase 1: acquire input into XP ----
    if (role==0){
      if (t>=16 && tid==0){
        while ((int)__hip_atomic_load(done, __ATOMIC_ACQUIRE, __HIP_MEMORY_SCOPE_AGENT) < t-15)
          __builtin_amdgcn_s_sleep(1);
      }
      const int node = tid>>3, f0 = (tid&7)*8;
      const float* src = input_seq + (((size_t)b*128 + t)*64 + node)*64 + f0;
      float4v v0 = *(const float4v*)(src);
      float4v v1 = *(const float4v*)(src+4);
      short8 hh, ll;
#pragma unroll
      for (int j=0;j<4;j++){
        unsigned short h0=f2bf(v0[j]); hh[j]=(short)h0; ll[j]=(short)f2bf(v0[j]-bf2f(h0));
        unsigned short h1=f2bf(v1[j]); hh[4+j]=(short)h1; ll[4+j]=(short)f2bf(v1[j]-bf2f(h1));
      }
      *(short8*)(lds_ + XP + node*72 + f0) = hh;
      *(short8*)(lds_ + XP + PLO + node*72 + f0) = ll;
      __syncthreads();
    } else {
      if (tid==0){
        while (__hip_atomic_load(&flags[t], __ATOMIC_ACQUIRE, __HIP_MEMORY_SCOPE_AGENT) != t+1)
          __builtin_amdgcn_s_sleep(1);
        __threadfence();
      }
      __syncthreads();
      if (w<4){
        const unsigned int* sl = slots + ((size_t)(b*16 + (t&15)))*4096 + (w*64+ln)*16;
#pragma unroll
        for (int Mt=0;Mt<4;Mt++){
          uint4v v = *(const uint4v*)(sl + Mt*4);
#pragma unroll
          for (int r=0;r<4;r++){
            const int o = XP + (16*Mt+4*qd+r)*72 + gcol;
            lds_[o] = (unsigned short)(v[r] & 0xffffu);
            lds_[o+PLO] = (unsigned short)(v[r] >> 16);
          }
        }
      }
      __syncthreads();
      if (tid==0)
        __hip_atomic_store(done, t+1, __ATOMIC_RELEASE, __HIP_MEMORY_SCOPE_AGENT);
    }

    // ---- phase 2: P1 r ----
    p1_group(lds_, WGf, 0, XP, HP, brv, gaccR, w, ln, fc, qd);
    __syncthreads();
    // ---- phase 3: P2 r (Z_r) ----
    p2_fused(lds_, sfA, sfB, sup, mt, fc, qd);
    __syncthreads();

    // ---- phase 4: P1 u + gate r (rh -> RH plane) ----
    p1_group(lds_, WGf, 1, XP, HP, buv, gaccU, w, ln, fc, qd);
    if (w<4){
      float4v pre[4]; read_pre(lds_, gaccR, pre, w, fc, qd);
      ushort4v oh[4], ol[4];
#pragma unroll
      for (int Mt=0;Mt<4;Mt++){
        float4v rh;
#pragma unroll
        for (int r=0;r<4;r++){
          float rv = 1.f/(1.f+__expf(-pre[Mt][r]));
          rh[r] = rv*h_old[Mt][r];
        }
        cvt_hilo(rh, oh[Mt], ol[Mt]);
      }
      scatter_plane(lds_, RH, w, fc, qd, oh, ol);
    }
    __syncthreads();
    // ---- phase 5: P2 u (Z_u overwrites Z_r, consumed) ----
    p2_fused(lds_, sfA, sfB, sup, mt, fc, qd);
    __syncthreads();

    // ---- phase 6: P1 c (A = XP | RH) + gate u ----
    p1_group(lds_, WCf, 0, XP, RH, bcv, gaccC, w, ln, fc, qd);
    if (w<4){
      float4v pre[4]; read_pre(lds_, gaccU, pre, w, fc, qd);
#pragma unroll
      for (int Mt=0;Mt<4;Mt++)
#pragma unroll
        for (int r=0;r<4;r++) uv[Mt][r] = 1.f/(1.f+__expf(-pre[Mt][r]));
    }
    __syncthreads();
    // ---- phase 7: P2 c ----
    p2_fused(lds_, sfA, sfB, sup, mt, fc, qd);
    __syncthreads();

    // ---- phase 8: update ----
    if (w<4){
      float4v pre[4]; read_pre(lds_, gaccC, pre, w, fc, qd);
      ushort4v oh[4], ol[4];
#pragma unroll
      for (int Mt=0;Mt<4;Mt++){
        float4v hn;
#pragma unroll
        for (int r=0;r<4;r++){
          float x = fminf(pre[Mt][r], 15.f);
          float e = __expf(2.f*x);
          float cv = (e-1.f)/(e+1.f);
          float u1 = uv[Mt][r];
          hn[r] = u1*h_old[Mt][r] + (1.f-u1)*cv;
        }
        h_old[Mt] = hn;
        cvt_hilo(hn, oh[Mt], ol[Mt]);
      }
      scatter_plane(lds_, HP, w, fc, qd, oh, ol);
      if (role==0){
        unsigned int* sl = slots + ((size_t)(b*16 + (t&15)))*4096 + (w*64+ln)*16;
#pragma unroll
        for (int Mt=0;Mt<4;Mt++){
          uint4v pk;
#pragma unroll
          for (int r=0;r<4;r++)
            pk[r] = (unsigned int)oh[Mt][r] | ((unsigned int)ol[Mt][r] << 16);
          *(uint4v*)(sl + Mt*4) = pk;
        }
      } else if (t==tl){
#pragma unroll
        for (int Mt=0;Mt<4;Mt++)
#pragma unroll
          for (int r=0;r<4;r++)
            capb[(16*Mt+4*qd+r)*64 + gcol] = oh[Mt][r];
      }
    }
    __syncthreads();
    if (role==0 && tid==0){
      __threadfence();
      __hip_atomic_store(&flags[t], t+1, __ATOMIC_RELEASE, __HIP_MEMORY_SCOPE_AGENT);
    }
  }

  if (role==0) return;

  __threadfence();
  __syncthreads();
  // epilogue (consumer): logits = relu(last_h2) @ Wp + bp; max over nodes
  float* sc = (float*)lds_;
  if (tid < 64){
    const unsigned short* hpx = capb + tid*64;
    float4v acc = {bp[0], bp[1], bp[2], bp[3]};
#pragma unroll 1
    for (int ch = 0; ch < 64; ++ch){
      float h = fmaxf(bf2f(hpx[ch]), 0.f);
      const float4v wr = *(const float4v*)(Wp + ch*4);
      acc += h * wr;
    }
    sc[tid*4+0]=acc[0]; sc[tid*4+1]=acc[1]; sc[tid*4+2]=acc[2]; sc[tid*4+3]=acc[3];
  }
  __syncthreads();
  if (tid < 4){
    float m = sc[tid];
#pragma unroll 1
    for (int n=1;n<64;n++) m = fmaxf(m, sc[n*4 + tid]);
    out[b*4 + tid] = m;
  }
}

// ---- S^2 (fp32) into ws scratch ----
__global__ void __launch_bounds__(256)
dcrnn_sq(const float* __restrict__ S0, const float* __restrict__ S1,
         float* __restrict__ sqs)
{
  const float* S = blockIdx.x ? S1 : S0;
  float* D = sqs + blockIdx.x*4096;
  const int i = threadIdx.x >> 2, j0 = (threadIdx.x & 3)*16;
  float acc[16];
#pragma unroll
  for (int j=0;j<16;j++) acc[j]=0.f;
#pragma unroll 4
  for (int k=0;k<64;k++){
    float s = S[i*64+k];
    const float* row = S + k*64 + j0;
#pragma unroll
    for (int j=0;j<16;j++) acc[j] += s*row[j];
  }
#pragma unroll
  for (int j=0;j<16;j++) D[i*64+j0+j]=acc[j];
}

// ---- prep: S, S^2 frags (A-layout) + folded W frags (B-layout), hi/lo ----
__global__ void __launch_bounds__(256)
dcrnn_prep(const float* __restrict__ S0, const float* __restrict__ S1,
           const float* __restrict__ Wg0, const float* __restrict__ Wc0,
           const float* __restrict__ Wg1, const float* __restrict__ Wc1,
           const float* __restrict__ sqs, unsigned short* __restrict__ frags)
{
  const int uid = blockIdx.x*256 + threadIdx.x;
  if (uid >= 65536) return;
  short8 o;
  unsigned short* dst;
  if (uid < 4096){
    int r = uid & 2047;
    const bool issq = uid >= 2048;
    const int lane = r & 63; r >>= 6;
    const int kt = r & 1; r >>= 1;
    const int Mt = r & 3; r >>= 2;
    const int pl = r & 1; r >>= 1;
    const float* S = issq ? (sqs + r*4096) : (r ? S1 : S0);
    const int m  = 16*Mt + (lane & 15);
    const int k0 = 32*kt + 8*(lane >> 4);
#pragma unroll
    for (int j=0;j<8;j++){
      float v = S[m*64 + k0 + j];
      unsigned short hi = f2bf(v);
      o[j] = (short)(pl ? f2bf(v - bf2f(hi)) : hi);
    }
    dst = frags + (issq ? WSF_S2 : 0) + (size_t)(uid & 2047)*8;
  } else {
    int u2 = uid - 4096;
    const float* W; int wld; size_t base;
    if      (u2 < 20480){ W = Wg0; wld = 128; base = WSF_WG0; }
    else if (u2 < 30720){ W = Wc0; wld = 64;  base = WSF_WC0; u2 -= 20480; }
    else if (u2 < 51200){ W = Wg1; wld = 128; base = WSF_WG1; u2 -= 30720; }
    else                { W = Wc1; wld = 64;  base = WSF_WC1; u2 -= 51200; }
    const int lane = u2 & 63;
    const int pl   = (u2 >> 6) & 1;
    const int rest = u2 >> 7;                 // ((grp*5+j)*4+nt)*4+kt
    const int kt = rest & 3;
    const int nt = (rest >> 2) & 3;
    const int j  = (rest >> 4) % 5;
    const int grp= (rest >> 4) / 5;
    const int col = grp*64 + 16*nt + (lane & 15);
    const int k0  = 32*kt + 8*(lane >> 4);
#pragma unroll
    for (int jj=0;jj<8;jj++){
      const int k = k0 + jj;
      float v;
      if (j == 0)
        v = W[(size_t)k*wld + col] - W[(size_t)(256+k)*wld + col] - W[(size_t)(512+k)*wld + col];
      else {
        v = W[(size_t)(j*128 + k)*wld + col];
        if (j == 2 || j == 4) v *= 2.f;
      }
      unsigned short hi = f2bf(v);
      o[jj] = (short)(pl ? f2bf(v - bf2f(hi)) : hi);
    }
    dst = frags + base + (size_t)u2*8;
  }
  *(short8*)dst = o;
}

extern "C" void kernel_launch(void* const* d_in, const int* in_sizes, int n_in,
                              void* d_out, int out_size, void* d_ws, size_t ws_size,
                              hipStream_t stream) {
  const float* input_seq   = (const float*)d_in[0];
  const int*   seq_lengths = (const int*)  d_in[1];
  const float* S0  = (const float*)d_in[2];
  const float* S1  = (const float*)d_in[3];
  const float* Wg0 = (const float*)d_in[4];
  const float* bg0 = (const float*)d_in[5];
  const float* Wc0 = (const float*)d_in[6];
  const float* bc0 = (const float*)d_in[7];
  const float* Wg1 = (const float*)d_in[8];
  const float* bg1 = (const float*)d_in[9];
  const float* Wc1 = (const float*)d_in[10];
  const float* bc1 = (const float*)d_in[11];
  const float* Wp  = (const float*)d_in[12];
  const float* bp  = (const float*)d_in[13];

  unsigned short* ws = (unsigned short*)d_ws;
  float* sqs = (float*)(ws + WSF_SQS);

  dcrnn_sq<<<dim3(2), dim3(256), 0, stream>>>(S0, S1, sqs);
  dcrnn_prep<<<dim3(256), dim3(256), 0, stream>>>(S0, S1, Wg0, Wc0, Wg1, Wc1, sqs, ws);

  (void)hipFuncSetAttribute((const void*)dcrnn_main,
                            hipFuncAttributeMaxDynamicSharedMemorySize, LDS_BYTES);
  dcrnn_main<<<dim3(64), dim3(512), LDS_BYTES, stream>>>(
      input_seq, seq_lengths, bg0, bc0, bg1, bc1, Wp, bp, ws, (float*)d_out);
}